// Round 5
// baseline (260272.852 us; speedup 1.0000x reference)
//
#include <hip/hip_runtime.h>
#include <hip/hip_bf16.h>
#include <math.h>

#define BB 256
#define TT 256
#define VV 33
#define HH 512
#define DD 256
#define KKEY 512
#define G4 2048

// =====================================================================
// DIAGNOSTIC ROUND: dead-simple pure-fp32 implementation.
// No MFMA, no bf16, no weight repacking, no custom layouts.
// All weights read directly in native [K, 4H] / [H, D] / [H+D, V] layouts.
// State in plain fp32 arrays; stream serialization = all ordering.
// =====================================================================

// z = bias + xcat@W + h_self@U   for one (col, all b)
// mode 1: xcat = [x_t (33) | a (256)],  W rows = 289
// mode 2: xcat = [h_prev (512) | a (256)], W rows = 768
__global__ __launch_bounds__(256) void z_naive(
    const float* __restrict__ x, const float* __restrict__ a,
    const float* __restrict__ hself, const float* __restrict__ hprev,
    const float* __restrict__ W, const float* __restrict__ U,
    const float* __restrict__ bias, float* __restrict__ z, int t, int mode)
{
    int col = blockIdx.x;    // 0..2047 (gate-major: i|f|g|o blocks of 512)
    int b = threadIdx.x;     // 0..255
    float s = bias[col];
    if (mode == 1) {
        for (int k = 0; k < VV; k++)
            s += x[((long)b * TT + t) * VV + k] * W[(long)k * G4 + col];
        for (int k = 0; k < DD; k++)
            s += a[b * DD + k] * W[(long)(VV + k) * G4 + col];
    } else {
        for (int k = 0; k < HH; k++)
            s += hprev[(long)b * HH + k] * W[(long)k * G4 + col];
        for (int k = 0; k < DD; k++)
            s += a[b * DD + k] * W[(long)(HH + k) * G4 + col];
    }
    for (int k = 0; k < HH; k++)
        s += hself[(long)b * HH + k] * U[(long)k * G4 + col];
    z[(long)b * G4 + col] = s;
}

// Keras LSTM gate update: z split [i|f|g|o] along 4H
__global__ __launch_bounds__(256) void gates_naive(
    const float* __restrict__ z, float* __restrict__ c, float* __restrict__ h)
{
    int idx = blockIdx.x * blockDim.x + threadIdx.x;  // b*HH + u
    int b = idx >> 9;          // /512
    int u = idx & (HH - 1);    // %512
    const float* zb = z + (long)b * G4;
    float zi = zb[u];
    float zf = zb[512 + u];
    float zg = zb[1024 + u];
    float zo = zb[1536 + u];
    float i_ = 1.f / (1.f + expf(-zi));
    float f_ = 1.f / (1.f + expf(-zf));
    float g_ = tanhf(zg);
    float o_ = 1.f / (1.f + expf(-zo));
    float cn = f_ * c[idx] + i_ * g_;
    c[idx] = cn;
    h[idx] = o_ * tanhf(cn);
}

// q = h @ Wq + bq
__global__ __launch_bounds__(256) void q_naive(
    const float* __restrict__ h, const float* __restrict__ Wq,
    const float* __restrict__ bq, float* __restrict__ q)
{
    int b = blockIdx.x, d = threadIdx.x;
    float s = bq[d];
    for (int j = 0; j < HH; j++)
        s += h[(long)b * HH + j] * Wq[(long)j * DD + d];
    q[b * DD + d] = s;
}

// a = softmax(keys . q) . keys   (one block per sample)
__global__ __launch_bounds__(256) void attn_naive(
    const float* __restrict__ q, const float* __restrict__ keys,
    float* __restrict__ a)
{
    __shared__ float slds[KKEY];
    __shared__ float red[8];
    int b = blockIdx.x, tid = threadIdx.x;
    int lane = tid & 63, wave = tid >> 6;
    const float* kb = keys + (long)b * KKEY * DD;
    const float* qb = q + b * DD;

    float s0 = 0.f, s1 = 0.f;
    for (int d = 0; d < DD; d++) {
        float qd = qb[d];
        s0 += kb[(long)tid * DD + d] * qd;
        s1 += kb[(long)(tid + 256) * DD + d] * qd;
    }
    float m = fmaxf(s0, s1);
    for (int o = 32; o > 0; o >>= 1) m = fmaxf(m, __shfl_xor(m, o));
    if (lane == 0) red[wave] = m;
    __syncthreads();
    m = fmaxf(fmaxf(red[0], red[1]), fmaxf(red[2], red[3]));

    float p0 = expf(s0 - m), p1 = expf(s1 - m);
    slds[tid] = p0;
    slds[tid + 256] = p1;
    float ps = p0 + p1;
    for (int o = 32; o > 0; o >>= 1) ps += __shfl_xor(ps, o);
    if (lane == 0) red[4 + wave] = ps;
    __syncthreads();
    float l = red[4] + red[5] + red[6] + red[7];

    // read phase: thread owns dim d = tid (coalesced across lanes)
    float acc = 0.f;
    for (int k = 0; k < KKEY; k++)
        acc += slds[k] * kb[(long)k * DD + tid];
    a[b * DD + tid] = acc / l;
}

// out[:, t, :] = concat(h3, a3) @ Wo + bo
__global__ __launch_bounds__(64) void out_naive(
    const float* __restrict__ h3, const float* __restrict__ a3,
    const float* __restrict__ Wo, const float* __restrict__ bo,
    float* __restrict__ out, int t)
{
    int b = blockIdx.x, v = threadIdx.x;
    if (v >= VV) return;
    float s = bo[v];
    for (int i = 0; i < HH; i++)
        s += h3[(long)b * HH + i] * Wo[(long)i * VV + v];
    for (int i = 0; i < DD; i++)
        s += a3[b * DD + i] * Wo[(long)(HH + i) * VV + v];
    out[((long)b * TT + t) * VV + v] = s;
}

// ---------------- launch ----------------

extern "C" void kernel_launch(void* const* d_in, const int* in_sizes, int n_in,
                              void* d_out, int out_size, void* d_ws, size_t ws_size,
                              hipStream_t stream) {
    // resolve inputs by size signature (matches documented dict order too)
    const float *x = nullptr, *keys = nullptr, *W1 = nullptr, *U1 = nullptr,
                *b1 = nullptr, *W2 = nullptr, *U2 = nullptr, *b2 = nullptr,
                *W3 = nullptr, *U3 = nullptr, *b3 = nullptr, *Wq = nullptr,
                *bq = nullptr, *Wo = nullptr, *bo = nullptr;
    {
        int cW23 = 0, cU = 0, cb = 0;
        for (int i = 0; i < n_in; i++) {
            const float* q = (const float*)d_in[i];
            switch (in_sizes[i]) {
                case 2162688:  x = q; break;                     // [256,256,33]
                case 33554432: keys = q; break;                  // [256,512,256]
                case 591872:   W1 = q; break;                    // [289,2048]
                case 1572864:  if (cW23 == 0) W2 = q; else W3 = q; cW23++; break;
                case 1048576:  if (cU == 0) U1 = q; else if (cU == 1) U2 = q; else U3 = q; cU++; break;
                case 2048:     if (cb == 0) b1 = q; else if (cb == 1) b2 = q; else b3 = q; cb++; break;
                case 131072:   Wq = q; break;                    // [512,256]
                case 256:      bq = q; break;
                case 25344:    Wo = q; break;                    // [768,33]
                case 33:       bo = q; break;
                default: break;
            }
        }
    }
    float* out = (float*)d_out;

    char* p = (char*)d_ws;
    auto alloc = [&](size_t n) { char* r = p; p += (n + 255) & ~(size_t)255; return r; };
    float* h1 = (float*)alloc((size_t)BB * HH * 4);
    float* c1 = (float*)alloc((size_t)BB * HH * 4);
    float* h2 = (float*)alloc((size_t)BB * HH * 4);
    float* c2 = (float*)alloc((size_t)BB * HH * 4);
    float* h3 = (float*)alloc((size_t)BB * HH * 4);
    float* c3 = (float*)alloc((size_t)BB * HH * 4);
    float* a  = (float*)alloc((size_t)BB * DD * 4);   // carry a (a3 from prev step)
    float* at = (float*)alloc((size_t)BB * DD * 4);   // within-step a1/a2
    float* zb = (float*)alloc((size_t)BB * G4 * 4);
    float* qb = (float*)alloc((size_t)BB * DD * 4);

    hipMemsetAsync(h1, 0, (size_t)BB * HH * 4, stream);
    hipMemsetAsync(c1, 0, (size_t)BB * HH * 4, stream);
    hipMemsetAsync(h2, 0, (size_t)BB * HH * 4, stream);
    hipMemsetAsync(c2, 0, (size_t)BB * HH * 4, stream);
    hipMemsetAsync(h3, 0, (size_t)BB * HH * 4, stream);
    hipMemsetAsync(c3, 0, (size_t)BB * HH * 4, stream);
    hipMemsetAsync(a,  0, (size_t)BB * DD * 4, stream);

    for (int t = 0; t < TT; t++) {
        // LSTM1: xcat = [x_t | a], self-recurrent h1
        z_naive<<<G4, 256, 0, stream>>>(x, a, h1, nullptr, W1, U1, b1, zb, t, 1);
        gates_naive<<<(BB * HH) / 256, 256, 0, stream>>>(zb, c1, h1);
        q_naive<<<BB, 256, 0, stream>>>(h1, Wq, bq, qb);
        attn_naive<<<BB, 256, 0, stream>>>(qb, keys, at);       // a1
        // LSTM2: xcat = [h1 | a1]
        z_naive<<<G4, 256, 0, stream>>>(x, at, h2, h1, W2, U2, b2, zb, t, 2);
        gates_naive<<<(BB * HH) / 256, 256, 0, stream>>>(zb, c2, h2);
        q_naive<<<BB, 256, 0, stream>>>(h2, Wq, bq, qb);
        attn_naive<<<BB, 256, 0, stream>>>(qb, keys, at);       // a2
        // LSTM3: xcat = [h2 | a2]
        z_naive<<<G4, 256, 0, stream>>>(x, at, h3, h2, W3, U3, b3, zb, t, 2);
        gates_naive<<<(BB * HH) / 256, 256, 0, stream>>>(zb, c3, h3);
        q_naive<<<BB, 256, 0, stream>>>(h3, Wq, bq, qb);
        attn_naive<<<BB, 256, 0, stream>>>(qb, keys, a);        // a3 -> next-step carry
        // out[:, t, :] = [h3 | a3] @ Wo + bo
        out_naive<<<BB, 64, 0, stream>>>(h3, a, Wo, bo, out, t);
    }
}

// Round 6
// 108338.855 us; speedup vs baseline: 2.4024x; 2.4024x over previous
//
#include <hip/hip_runtime.h>
#include <hip/hip_bf16.h>
#include <math.h>

#define BB 256
#define TT 256
#define VV 33
#define HH 512
#define DD 256
#define KKEY 512
#define G4 2048
#define K1P 832    // [x(33) | a(256) | h1(512)] = 801, padded to 832 (26 k-chunks)
#define K2P 1280   // [hprev(512) | a(256) | hself(512)] = 1280 (40 k-chunks)

typedef unsigned short u16;
typedef unsigned int u32;
typedef __attribute__((ext_vector_type(8))) short short8;
typedef __attribute__((ext_vector_type(4))) float float4v;

__device__ inline float bf2f(u16 v) {
    union { u32 u; float f; } c; c.u = ((u32)v) << 16; return c.f;
}
__device__ inline u16 f2bf(float f) {
    __hip_bfloat16 h = __float2bfloat16(f);
    union { __hip_bfloat16 h; u16 u; } c; c.h = h; return c.u;
}
__device__ inline void split_bf(float v, u16& hi, u16& lo) {
    hi = f2bf(v);
    lo = f2bf(v - bf2f(hi));
}

// ---------------- weight prep: Wt[col][k], natural gate-major col order ----------------
__global__ void prep_v6(const float* __restrict__ W, const float* __restrict__ U,
                        u16* __restrict__ WtH, u16* __restrict__ WtL, int Kd, int mode) {
    long idx = (long)blockIdx.x * blockDim.x + threadIdx.x;
    if (idx >= (long)G4 * Kd) return;
    int col = (int)(idx / Kd);
    int k = (int)(idx % Kd);
    float v = 0.f;
    if (mode == 1) {
        // xcat rows: [x(0:33) -> W rows 0:33 | a(33:289) -> W rows 33:289 | h1(289:801) -> U]
        if (k < 289)      v = W[(long)k * G4 + col];
        else if (k < 801) v = U[(long)(k - 289) * G4 + col];
    } else {
        // xcat rows: [hprev(0:512) | a(512:768)] -> W rows 0:768 | hself(768:1280) -> U
        if (k < 768)       v = W[(long)k * G4 + col];
        else               v = U[(long)(k - 768) * G4 + col];
    }
    u16 hi, lo; split_bf(v, hi, lo);
    WtH[idx] = hi; WtL[idx] = lo;
}

// ---------------- pack xcat[b][k] (bf16 hi/lo) from fp32 sources ----------------
__global__ void pack_v6(const float* __restrict__ x, const float* __restrict__ a,
                        const float* __restrict__ hp, const float* __restrict__ hs,
                        u16* __restrict__ H, u16* __restrict__ L, int Kd, int t, int mode) {
    long idx = (long)blockIdx.x * blockDim.x + threadIdx.x;
    if (idx >= (long)BB * Kd) return;
    int b = (int)(idx / Kd);
    int k = (int)(idx % Kd);
    float v = 0.f;
    if (mode == 1) {
        if (k < 33)       v = x[((long)b * TT + t) * VV + k];
        else if (k < 289) v = a[b * DD + (k - 33)];
        else if (k < 801) v = hs[(long)b * HH + (k - 289)];
    } else {
        if (k < 512)       v = hp[(long)b * HH + k];
        else if (k < 768)  v = a[b * DD + (k - 512)];
        else               v = hs[(long)b * HH + (k - 768)];
    }
    u16 hi, lo; split_bf(v, hi, lo);
    H[idx] = hi; L[idx] = lo;
}

// ---------------- z-GEMM: z[b][col] = bias[col] + xcat[b][:] . Wt[col][:] ----------------
// bf16x3: A*B ~= Ah*Bh + Ah*Bl + Al*Bh. grid 128 = 4 m-tiles x 32 n-tiles, 256 thr.
__global__ __launch_bounds__(256) void zmfma_v6(
    const u16* __restrict__ aH, const u16* __restrict__ aL, int Kd,
    const u16* __restrict__ wH, const u16* __restrict__ wL,
    const float* __restrict__ bias, float* __restrict__ z)
{
    __shared__ u16 AldsH[64 * 40];
    __shared__ u16 AldsL[64 * 40];
    __shared__ u16 WldsH[64 * 40];
    __shared__ u16 WldsL[64 * 40];

    int tid = threadIdx.x;
    int mt = blockIdx.x >> 5;    // 0..3
    int nt = blockIdx.x & 31;    // 0..31
    int M0 = mt * 64, N0 = nt * 64;

    int wave = tid >> 6, lane = tid & 63;
    int lr = lane & 15, lg = lane >> 4;
    int srow = tid >> 2, spart = tid & 3;

    const u16* aHB = aH + (long)(M0 + srow) * Kd + spart * 8;
    const u16* aLB = aL + (long)(M0 + srow) * Kd + spart * 8;
    const u16* wHB = wH + (long)(N0 + srow) * Kd + spart * 8;
    const u16* wLB = wL + (long)(N0 + srow) * Kd + spart * 8;

    float4v acc[4];
    #pragma unroll
    for (int i = 0; i < 4; i++) acc[i] = (float4v){0.f, 0.f, 0.f, 0.f};

    for (int k0 = 0; k0 < Kd; k0 += 32) {
        __syncthreads();
        *(uint4*)(&AldsH[srow * 40 + spart * 8]) = *(const uint4*)(aHB + k0);
        *(uint4*)(&AldsL[srow * 40 + spart * 8]) = *(const uint4*)(aLB + k0);
        *(uint4*)(&WldsH[srow * 40 + spart * 8]) = *(const uint4*)(wHB + k0);
        *(uint4*)(&WldsL[srow * 40 + spart * 8]) = *(const uint4*)(wLB + k0);
        __syncthreads();
        // A fragment: m = wave*16 + (lane&15), k = (lane>>4)*8 + j   [m120-verified]
        short8 ah = *(const short8*)(&AldsH[(wave * 16 + lr) * 40 + lg * 8]);
        short8 al = *(const short8*)(&AldsL[(wave * 16 + lr) * 40 + lg * 8]);
        #pragma unroll
        for (int tt = 0; tt < 4; tt++) {
            // B^T fragment: n = tt*16 + (lane&15), k = (lane>>4)*8 + j
            short8 bh = *(const short8*)(&WldsH[(tt * 16 + lr) * 40 + lg * 8]);
            short8 bl = *(const short8*)(&WldsL[(tt * 16 + lr) * 40 + lg * 8]);
            acc[tt] = __builtin_amdgcn_mfma_f32_16x16x32_bf16(ah, bh, acc[tt], 0, 0, 0);
            acc[tt] = __builtin_amdgcn_mfma_f32_16x16x32_bf16(ah, bl, acc[tt], 0, 0, 0);
            acc[tt] = __builtin_amdgcn_mfma_f32_16x16x32_bf16(al, bh, acc[tt], 0, 0, 0);
        }
    }

    // D: col = lane&15 (within 16-block), row m = (lane>>4)*4 + r   [m89-verified]
    #pragma unroll
    for (int tt = 0; tt < 4; tt++) {
        int col = N0 + tt * 16 + lr;
        float bv = bias[col];
        #pragma unroll
        for (int r = 0; r < 4; r++) {
            int m = M0 + wave * 16 + lg * 4 + r;
            z[(long)m * G4 + col] = acc[tt][r] + bv;
        }
    }
}

// ---------------- gates (unchanged from passing naive) ----------------
__global__ __launch_bounds__(256) void gates_naive(
    const float* __restrict__ z, float* __restrict__ c, float* __restrict__ h)
{
    int idx = blockIdx.x * blockDim.x + threadIdx.x;  // b*HH + u
    int u = idx & (HH - 1);
    int b = idx >> 9;
    const float* zb = z + (long)b * G4;
    float zi = zb[u];
    float zf = zb[512 + u];
    float zg = zb[1024 + u];
    float zo = zb[1536 + u];
    float i_ = 1.f / (1.f + expf(-zi));
    float f_ = 1.f / (1.f + expf(-zf));
    float g_ = tanhf(zg);
    float o_ = 1.f / (1.f + expf(-zo));
    float cn = f_ * c[idx] + i_ * g_;
    c[idx] = cn;
    h[idx] = o_ * tanhf(cn);
}

// ---------------- q = h @ Wq + bq ----------------
__global__ __launch_bounds__(256) void q_naive(
    const float* __restrict__ h, const float* __restrict__ Wq,
    const float* __restrict__ bq, float* __restrict__ q)
{
    int b = blockIdx.x, d = threadIdx.x;
    float s = bq[d];
    const float* hb = h + (long)b * HH;
    #pragma unroll 4
    for (int j = 0; j < HH; j++)
        s += hb[j] * Wq[(long)j * DD + d];
    q[b * DD + d] = s;
}

// ---------------- attention (fp32 keys, one block per sample) ----------------
__global__ __launch_bounds__(256) void attn_naive(
    const float* __restrict__ q, const float* __restrict__ keys,
    float* __restrict__ a)
{
    __shared__ float slds[KKEY];
    __shared__ float red[8];
    int b = blockIdx.x, tid = threadIdx.x;
    int lane = tid & 63, wave = tid >> 6;
    const float* kb = keys + (long)b * KKEY * DD;
    const float* qb = q + b * DD;

    float s0 = 0.f, s1 = 0.f;
    const float* kr0 = kb + (long)tid * DD;
    const float* kr1 = kb + (long)(tid + 256) * DD;
    for (int d = 0; d < DD; d += 4) {
        float4 k0 = *(const float4*)(kr0 + d);
        float4 k1 = *(const float4*)(kr1 + d);
        float q0 = qb[d], q1 = qb[d + 1], q2 = qb[d + 2], q3 = qb[d + 3];
        s0 += k0.x * q0 + k0.y * q1 + k0.z * q2 + k0.w * q3;
        s1 += k1.x * q0 + k1.y * q1 + k1.z * q2 + k1.w * q3;
    }
    float m = fmaxf(s0, s1);
    for (int o = 32; o > 0; o >>= 1) m = fmaxf(m, __shfl_xor(m, o));
    if (lane == 0) red[wave] = m;
    __syncthreads();
    m = fmaxf(fmaxf(red[0], red[1]), fmaxf(red[2], red[3]));

    float p0 = expf(s0 - m), p1 = expf(s1 - m);
    slds[tid] = p0;
    slds[tid + 256] = p1;
    float ps = p0 + p1;
    for (int o = 32; o > 0; o >>= 1) ps += __shfl_xor(ps, o);
    if (lane == 0) red[4 + wave] = ps;
    __syncthreads();
    float l = red[4] + red[5] + red[6] + red[7];

    float acc = 0.f;
    for (int k = 0; k < KKEY; k++)
        acc += slds[k] * kb[(long)k * DD + tid];
    a[b * DD + tid] = acc / l;
}

// ---------------- out[:, t, :] = concat(h3, a3) @ Wo + bo ----------------
__global__ __launch_bounds__(64) void out_naive(
    const float* __restrict__ h3, const float* __restrict__ a3,
    const float* __restrict__ Wo, const float* __restrict__ bo,
    float* __restrict__ out, int t)
{
    int b = blockIdx.x, v = threadIdx.x;
    if (v >= VV) return;
    float s = bo[v];
    for (int i = 0; i < HH; i++)
        s += h3[(long)b * HH + i] * Wo[(long)i * VV + v];
    for (int i = 0; i < DD; i++)
        s += a3[b * DD + i] * Wo[(long)(HH + i) * VV + v];
    out[((long)b * TT + t) * VV + v] = s;
}

// ---------------- launch ----------------

extern "C" void kernel_launch(void* const* d_in, const int* in_sizes, int n_in,
                              void* d_out, int out_size, void* d_ws, size_t ws_size,
                              hipStream_t stream) {
    const float *x = nullptr, *keys = nullptr, *W1 = nullptr, *U1 = nullptr,
                *b1 = nullptr, *W2 = nullptr, *U2 = nullptr, *b2 = nullptr,
                *W3 = nullptr, *U3 = nullptr, *b3 = nullptr, *Wq = nullptr,
                *bq = nullptr, *Wo = nullptr, *bo = nullptr;
    {
        int cW23 = 0, cU = 0, cb = 0;
        for (int i = 0; i < n_in; i++) {
            const float* q = (const float*)d_in[i];
            switch (in_sizes[i]) {
                case 2162688:  x = q; break;
                case 33554432: keys = q; break;
                case 591872:   W1 = q; break;
                case 1572864:  if (cW23 == 0) W2 = q; else W3 = q; cW23++; break;
                case 1048576:  if (cU == 0) U1 = q; else if (cU == 1) U2 = q; else U3 = q; cU++; break;
                case 2048:     if (cb == 0) b1 = q; else if (cb == 1) b2 = q; else b3 = q; cb++; break;
                case 131072:   Wq = q; break;
                case 256:      bq = q; break;
                case 25344:    Wo = q; break;
                case 33:       bo = q; break;
                default: break;
            }
        }
    }
    float* out = (float*)d_out;

    char* p = (char*)d_ws;
    auto alloc = [&](size_t n) { char* r = p; p += (n + 255) & ~(size_t)255; return r; };
    // weights (bf16 hi/lo, transposed [col][k])
    u16* WtH1 = (u16*)alloc((size_t)G4 * K1P * 2);
    u16* WtL1 = (u16*)alloc((size_t)G4 * K1P * 2);
    u16* WtH2 = (u16*)alloc((size_t)G4 * K2P * 2);
    u16* WtL2 = (u16*)alloc((size_t)G4 * K2P * 2);
    u16* WtH3 = (u16*)alloc((size_t)G4 * K2P * 2);
    u16* WtL3 = (u16*)alloc((size_t)G4 * K2P * 2);
    // xcat staging (bf16 hi/lo), one per layer
    u16* xcH1 = (u16*)alloc((size_t)BB * K1P * 2);
    u16* xcL1 = (u16*)alloc((size_t)BB * K1P * 2);
    u16* xcH2 = (u16*)alloc((size_t)BB * K2P * 2);
    u16* xcL2 = (u16*)alloc((size_t)BB * K2P * 2);
    u16* xcH3 = (u16*)alloc((size_t)BB * K2P * 2);
    u16* xcL3 = (u16*)alloc((size_t)BB * K2P * 2);
    // fp32 state
    float* h1 = (float*)alloc((size_t)BB * HH * 4);
    float* c1 = (float*)alloc((size_t)BB * HH * 4);
    float* h2 = (float*)alloc((size_t)BB * HH * 4);
    float* c2 = (float*)alloc((size_t)BB * HH * 4);
    float* h3 = (float*)alloc((size_t)BB * HH * 4);
    float* c3 = (float*)alloc((size_t)BB * HH * 4);
    float* a  = (float*)alloc((size_t)BB * DD * 4);
    float* at = (float*)alloc((size_t)BB * DD * 4);
    float* zb = (float*)alloc((size_t)BB * G4 * 4);
    float* qb = (float*)alloc((size_t)BB * DD * 4);

    // prep
    {
        long t1 = (long)G4 * K1P;
        prep_v6<<<(int)((t1 + 255) / 256), 256, 0, stream>>>(W1, U1, WtH1, WtL1, K1P, 1);
        long t2 = (long)G4 * K2P;
        prep_v6<<<(int)((t2 + 255) / 256), 256, 0, stream>>>(W2, U2, WtH2, WtL2, K2P, 2);
        prep_v6<<<(int)((t2 + 255) / 256), 256, 0, stream>>>(W3, U3, WtH3, WtL3, K2P, 2);
        hipMemsetAsync(h1, 0, (size_t)BB * HH * 4, stream);
        hipMemsetAsync(c1, 0, (size_t)BB * HH * 4, stream);
        hipMemsetAsync(h2, 0, (size_t)BB * HH * 4, stream);
        hipMemsetAsync(c2, 0, (size_t)BB * HH * 4, stream);
        hipMemsetAsync(h3, 0, (size_t)BB * HH * 4, stream);
        hipMemsetAsync(c3, 0, (size_t)BB * HH * 4, stream);
        hipMemsetAsync(a,  0, (size_t)BB * DD * 4, stream);
    }

    int g1 = (BB * K1P + 255) / 256;
    int g2 = (BB * K2P + 255) / 256;

    for (int t = 0; t < TT; t++) {
        // LSTM1: xcat = [x_t | a | h1]
        pack_v6<<<g1, 256, 0, stream>>>(x, a, nullptr, h1, xcH1, xcL1, K1P, t, 1);
        zmfma_v6<<<128, 256, 0, stream>>>(xcH1, xcL1, K1P, WtH1, WtL1, b1, zb);
        gates_naive<<<(BB * HH) / 256, 256, 0, stream>>>(zb, c1, h1);
        q_naive<<<BB, 256, 0, stream>>>(h1, Wq, bq, qb);
        attn_naive<<<BB, 256, 0, stream>>>(qb, keys, at);        // a1
        // LSTM2: xcat = [h1 | a1 | h2]
        pack_v6<<<g2, 256, 0, stream>>>(nullptr, at, h1, h2, xcH2, xcL2, K2P, t, 2);
        zmfma_v6<<<128, 256, 0, stream>>>(xcH2, xcL2, K2P, WtH2, WtL2, b2, zb);
        gates_naive<<<(BB * HH) / 256, 256, 0, stream>>>(zb, c2, h2);
        q_naive<<<BB, 256, 0, stream>>>(h2, Wq, bq, qb);
        attn_naive<<<BB, 256, 0, stream>>>(qb, keys, at);        // a2
        // LSTM3: xcat = [h2 | a2 | h3]
        pack_v6<<<g2, 256, 0, stream>>>(nullptr, at, h2, h3, xcH3, xcL3, K2P, t, 2);
        zmfma_v6<<<128, 256, 0, stream>>>(xcH3, xcL3, K2P, WtH3, WtL3, b3, zb);
        gates_naive<<<(BB * HH) / 256, 256, 0, stream>>>(zb, c3, h3);
        q_naive<<<BB, 256, 0, stream>>>(h3, Wq, bq, qb);
        attn_naive<<<BB, 256, 0, stream>>>(qb, keys, a);         // a3 (next-step carry)
        // out
        out_naive<<<BB, 64, 0, stream>>>(h3, a, Wo, bo, out, t);
    }
}